// Round 17
// baseline (644.189 us; speedup 1.0000x reference)
//
#include <hip/hip_runtime.h>

#define B_DIM 64
#define T_DIM 524288
#define D_FAC 16
#define LBLK 64          // frames per composed block
#define NB 512           // blocks per row
#define NBLK_TOT 32768   // total blocks (B*NB)
#define CSTR 72          // padded stride (floats) of one block map (16B-aligned)
#define PF 4             // scanner prefetch depth (blocks), group-local
#define EPSV 1e-7f
#define BIGC 1e30f

// 20*log10(2)
#define DB_PER_LOG2 6.0205999132796239f
// log2(10)/20
#define L2TEN_OVER20 0.16609640474436813f

__device__ __forceinline__ float sum_log2_4(float4 x) {
  return __log2f(fabsf(x.x) + EPSV) + __log2f(fabsf(x.y) + EPSV) +
         __log2f(fabsf(x.z) + EPSV) + __log2f(fabsf(x.w) + EPSV);
}

template <int CTRL, int RM>
__device__ __forceinline__ float fmin_dpp_step(float v) {
  int vi = __float_as_int(v);
  int sh = __builtin_amdgcn_update_dpp(vi, vi, CTRL, RM, 0xf, false);
  return fminf(v, __int_as_float(sh));
}

// Fused K1+K2 with per-block done FLAGS (r16 ERRATA: a per-row COUNTER
// does not imply prefix completion -- worker blocks finish out of order).
// Blocks 0..63: per-row scanners (wave 0 only); scanner group j spins until
// flags[j*64+lane] are ALL set (prefix-exact), then acquire-fences and
// computes. Blocks 64..8255: k1 workers; each wave stores its 65 consts,
// release-fences, sets its flag. Workers never wait -> no deadlock.
__global__ __launch_bounds__(256) void k1k2_fused(
    const float* __restrict__ audio, const float* __restrict__ p_thr,
    const float* __restrict__ p_ratio, const float* __restrict__ p_att,
    const float* __restrict__ p_rel, float* __restrict__ consts,
    float* __restrict__ states, int* __restrict__ flags) {
  const float A = p_att[0], R = p_rel[0];
  const int bid = blockIdx.x;

  if (bid >= 64) {
    // ---------------- k1 worker ----------------
    __shared__ float cab[4][128];  // per wave: [2t]=ca_t, [2t+1]=cr_t
    const int tid = threadIdx.x;
    const int lane = tid & 63;
    const int w = tid >> 6;
    const int gblk = (bid - 64) * 4 + w;  // 0..32767
    const int row = gblk >> 9;
    const int b = gblk & (NB - 1);
    const float thr = p_thr[0];
    const float oneA = 1.f - A, oneR = 1.f - R;
    const float gslope = (1.f / p_ratio[0]) - 1.f;

    const size_t sbase =
        (size_t)row * T_DIM + (size_t)(b * LBLK + lane) * D_FAC;
    const float4* ap = (const float4*)(audio + sbase);
    float s = sum_log2_4(ap[0]) + sum_log2_4(ap[1]) + sum_log2_4(ap[2]) +
              sum_log2_4(ap[3]);
    float xdb = s * (DB_PER_LOG2 / 16.f);
    float g = fminf(0.f, (xdb - thr) * gslope);

    cab[w][2 * lane] = oneA * g;
    cab[w][2 * lane + 1] = oneR * g;

    const float2* cp = (const float2*)cab[w];
    float c = (lane == 0) ? 0.f : BIGC;
    float c64 = BIGC;
#pragma unroll
    for (int t = 0; t < LBLK; ++t) {
      float2 cc = cp[t];  // uniform address -> LDS broadcast
      float prev = __int_as_float(__builtin_amdgcn_update_dpp(
          __float_as_int(BIGC), __float_as_int(c), 0x138 /*wave_shr:1*/, 0xf,
          0xf, false));
      c64 = fminf(fmaf(A, c, cc.x), fmaf(R, c64, cc.y));
      c = fminf(fmaf(A, prev, cc.x), fmaf(R, c, cc.y));
    }
    float* outp = consts + (size_t)gblk * CSTR;
    outp[lane] = c;
    if (lane == 63) {
#pragma unroll
      for (int j = 0; j < 8; ++j) outp[64 + j] = c64;
      // all 64 lanes' stores are this wave's program-order predecessors
      __builtin_amdgcn_fence(__ATOMIC_RELEASE, "agent");
      __hip_atomic_store(&flags[gblk], 1, __ATOMIC_RELAXED,
                         __HIP_MEMORY_SCOPE_AGENT);
    }
    return;
  }

  // ---------------- k2 scanner (row = bid) ----------------
  if (threadIdx.x >= 64) return;  // wave 0 only
  const int r = bid;
  const int lane = threadIdx.x;
  const int cls0 = (lane < 8) ? 8 * lane : 64;
  float s0 = 1.f;
  for (int i = 0; i < 64; ++i) s0 *= (i < cls0) ? A : R;  // A^cls0 R^(64-cls0)
  const float rAR = A / R;
  const float sl0 = s0, sl1 = sl0 * rAR, sl2 = sl1 * rAR, sl3 = sl2 * rAR,
              sl4 = sl3 * rAR, sl5 = sl4 * rAR, sl6 = sl5 * rAR,
              sl7 = sl6 * rAR;
  const int loff = (lane < 8) ? 8 * lane : 64;

  const float* base = consts + (size_t)r * NB * CSTR;
  float* st = states + r * NB;
  const int* fbase = flags + r * NB;

  float p = 0.f;
  for (int j = 0; j < 8; ++j) {  // 8 groups of 64 blocks
    // wait until ALL of this group's 64 blocks are flagged (prefix-exact:
    // lane l watches block j*64+l)
    int fl = 0;
    while (!__all(fl)) {
      if (!fl)
        fl = __hip_atomic_load(&fbase[j * 64 + lane], __ATOMIC_RELAXED,
                               __HIP_MEMORY_SCOPE_AGENT);
      if (!__all(fl)) __builtin_amdgcn_s_sleep(2);
    }
    __builtin_amdgcn_fence(__ATOMIC_ACQUIRE, "agent");

    // group-local prefetch (blocks j*64 .. j*64+PF-1)
    float4 qa[PF], qb[PF];
#pragma unroll
    for (int u = 0; u < PF; ++u) {
      qa[u] = *(const float4*)(base + (j * 64 + u) * CSTR + loff);
      qb[u] = *(const float4*)(base + (j * 64 + u) * CSTR + loff + 4);
    }
    float sj = 0.f;  // lane i holds state of block j*64+i
    for (int k = 0; k < 16; ++k) {
#pragma unroll
      for (int u = 0; u < PF; ++u) {
        const int i = k * PF + u;       // step within group (uniform)
        const int b2 = j * 64 + i;      // global block
        float f0 = fmaf(sl0, p, qa[u].x);
        float f1 = fmaf(sl1, p, qa[u].y);
        float f2 = fmaf(sl2, p, qa[u].z);
        float f3 = fmaf(sl3, p, qa[u].w);
        float f4 = fmaf(sl4, p, qb[u].x);
        float f5 = fmaf(sl5, p, qb[u].y);
        float f6 = fmaf(sl6, p, qb[u].z);
        float f7 = fmaf(sl7, p, qb[u].w);
        float m = fminf(fminf(fminf(f0, f1), f2),
                        fminf(fminf(fminf(f3, f4), f5), fminf(f6, f7)));
        m = fmin_dpp_step<0x111, 0xf>(m);  // row_shr:1
        m = fmin_dpp_step<0x112, 0xf>(m);  // row_shr:2
        m = fmin_dpp_step<0x114, 0xf>(m);  // row_shr:4 -> lane7 = min(0..7)
        m = fmin_dpp_step<0x111, 0xf>(m);  // fold lane7 agg into lane8
        sj = (lane == i) ? p : sj;  // state at START of block b2 (old p)
        p = __int_as_float(__builtin_amdgcn_readlane(__float_as_int(m), 8));
        // refill slot u with block b2+PF, clamped inside the flagged group
        // (clamped refills land in the last PF steps and are never consumed)
        int nb2 = b2 + PF;
        int gend = j * 64 + 63;
        nb2 = (nb2 < gend) ? nb2 : gend;
        qa[u] = *(const float4*)(base + nb2 * CSTR + loff);
        qb[u] = *(const float4*)(base + nb2 * CSTR + loff + 4);
      }
    }
    st[j * 64 + lane] = sj;
  }
}

// K3: one wave per block; lane owns one frame (16 samples in regs); wave
// replays the 64-step recurrence from the block-start state; applies gain.
// Plain float4 stores (r14 ERRATA: NT stores -> partial-line RMW, 2x WRITE).
__global__ __launch_bounds__(256) void k3_apply(
    const float* __restrict__ audio, const float* __restrict__ states,
    const float* __restrict__ p_thr, const float* __restrict__ p_ratio,
    const float* __restrict__ p_makeup, const float* __restrict__ p_att,
    const float* __restrict__ p_rel, float* __restrict__ out) {
  const int tid = threadIdx.x;
  const int lane = tid & 63;
  const int w = tid >> 6;
  const int gblk = blockIdx.x * 4 + w;  // 0..32767
  const int row = gblk >> 9;
  const int b = gblk & (NB - 1);
  const float thr = p_thr[0], ratio = p_ratio[0], mk = p_makeup[0];
  const float A = p_att[0], R = p_rel[0];
  const float oneA = 1.f - A, oneR = 1.f - R;
  const float gslope = (1.f / ratio) - 1.f;

  const size_t sbase = (size_t)row * T_DIM + (size_t)(b * LBLK + lane) * D_FAC;
  const float4* ap = (const float4*)(audio + sbase);
  float4 x0 = ap[0], x1 = ap[1], x2 = ap[2], x3 = ap[3];
  float s = sum_log2_4(x0) + sum_log2_4(x1) + sum_log2_4(x2) + sum_log2_4(x3);
  float xdb = s * (DB_PER_LOG2 / 16.f);
  float g = fminf(0.f, (xdb - thr) * gslope);

  float p = states[gblk];
  float m = 0.f;
  int gi = __float_as_int(g);
#pragma unroll
  for (int t = 0; t < LBLK; ++t) {
    float gt = __int_as_float(__builtin_amdgcn_readlane(gi, t));
    p = fminf(fmaf(A, p, oneA * gt), fmaf(R, p, oneR * gt));
    m = (lane == t) ? p : m;
  }
  float mult = exp2f((m + mk) * L2TEN_OVER20);
  float4* op = (float4*)(out + sbase);
  float4 y0, y1, y2, y3;
  y0.x = x0.x * mult; y0.y = x0.y * mult; y0.z = x0.z * mult; y0.w = x0.w * mult;
  y1.x = x1.x * mult; y1.y = x1.y * mult; y1.z = x1.z * mult; y1.w = x1.w * mult;
  y2.x = x2.x * mult; y2.y = x2.y * mult; y2.z = x2.z * mult; y2.w = x2.w * mult;
  y3.x = x3.x * mult; y3.y = x3.y * mult; y3.z = x3.z * mult; y3.w = x3.w * mult;
  op[0] = y0; op[1] = y1; op[2] = y2; op[3] = y3;
}

extern "C" void kernel_launch(void* const* d_in, const int* in_sizes, int n_in,
                              void* d_out, int out_size, void* d_ws,
                              size_t ws_size, hipStream_t stream) {
  const float* audio = (const float*)d_in[0];
  const float* thr = (const float*)d_in[1];
  const float* ratio = (const float*)d_in[2];
  const float* makeup = (const float*)d_in[3];
  const float* att = (const float*)d_in[4];
  const float* rel = (const float*)d_in[5];
  float* out = (float*)d_out;

  const size_t CONSTS_BYTES = (size_t)NBLK_TOT * CSTR * sizeof(float);  // ~9.4 MB
  const size_t STATES_BYTES = (size_t)NBLK_TOT * sizeof(float);         // 128 KB

  float* consts = (float*)d_ws;
  float* states = (float*)((char*)d_ws + CONSTS_BYTES);
  int* flags = (int*)((char*)d_ws + CONSTS_BYTES + STATES_BYTES);

  // zero per-block done flags (graph-safe, runs every call -> deterministic)
  hipMemsetAsync(flags, 0, NBLK_TOT * sizeof(int), stream);

  hipLaunchKernelGGL(k1k2_fused, dim3(64 + 8192), dim3(256), 0, stream, audio,
                     thr, ratio, att, rel, consts, states, flags);
  hipLaunchKernelGGL(k3_apply, dim3(8192), dim3(256), 0, stream, audio, states,
                     thr, ratio, makeup, att, rel, out);
}

// Round 18
// 165.541 us; speedup vs baseline: 3.8914x; 3.8914x over previous
//
#include <hip/hip_runtime.h>

#define B_DIM 64
#define T_DIM 524288
#define D_FAC 16
#define LBLK 128         // frames per composed block
#define NB 256           // blocks per row
#define NBLK_TOT 16384   // total blocks (B*NB)
#define NCLS 129         // LBLK+1 slope classes
#define CSTR 132         // padded stride (floats) of one block map (16B-aligned)
#define PF 16            // K2 prefetch depth (blocks)
#define PADBLK 16        // consts tail pad (blocks) for prefetch overrun
#define EPSV 1e-7f
#define BIGC 1e30f

// 20*log10(2)
#define DB_PER_LOG2 6.0205999132796239f
// log2(10)/20
#define L2TEN_OVER20 0.16609640474436813f

__device__ __forceinline__ float sum_log2_4(float4 x) {
  return __log2f(fabsf(x.x) + EPSV) + __log2f(fabsf(x.y) + EPSV) +
         __log2f(fabsf(x.z) + EPSV) + __log2f(fabsf(x.w) + EPSV);
}

template <int CTRL, int RM>
__device__ __forceinline__ float fmin_dpp_step(float v) {
  int vi = __float_as_int(v);
  int sh = __builtin_amdgcn_update_dpp(vi, vi, CTRL, RM, 0xf, false);
  return fminf(v, __int_as_float(sh));
}

// K1: one wave per 128-frame block. Lane computes g for frames
// {b*128+lane, b*128+64+lane} (8 upfront float4 loads), stages ca/cr into
// LDS, then class-parallel DP: lane holds classes {2l, 2l+1}; class 2l
// needs 2l-1 (= lane l-1's second slot -> one wave_shr:1 DPP); 2l+1 needs
// own 2l; class 128 rides on lane 63 (needs only own c127).
__global__ __launch_bounds__(256) void k1_compose(
    const float* __restrict__ audio, const float* __restrict__ p_thr,
    const float* __restrict__ p_ratio, const float* __restrict__ p_att,
    const float* __restrict__ p_rel, float* __restrict__ consts) {
  __shared__ float cab[4][256];  // per wave: [2t]=ca_t, [2t+1]=cr_t
  const int tid = threadIdx.x;
  const int lane = tid & 63;
  const int w = tid >> 6;
  const int gblk = blockIdx.x * 4 + w;  // 0..16383
  const int row = gblk >> 8;
  const int b = gblk & (NB - 1);
  const float thr = p_thr[0];
  const float A = p_att[0], R = p_rel[0];
  const float oneA = 1.f - A, oneR = 1.f - R;
  const float gslope = (1.f / p_ratio[0]) - 1.f;

  const size_t base0 =
      (size_t)row * T_DIM + (size_t)(b * LBLK + lane) * D_FAC;
  const float4* ap0 = (const float4*)(audio + base0);
  const float4* ap1 = (const float4*)(audio + base0 + 64 * D_FAC);
  float4 x0 = ap0[0], x1 = ap0[1], x2 = ap0[2], x3 = ap0[3];
  float4 x4 = ap1[0], x5 = ap1[1], x6 = ap1[2], x7 = ap1[3];
  float s0 = sum_log2_4(x0) + sum_log2_4(x1) + sum_log2_4(x2) + sum_log2_4(x3);
  float s1 = sum_log2_4(x4) + sum_log2_4(x5) + sum_log2_4(x6) + sum_log2_4(x7);
  float g0 = fminf(0.f, (s0 * (DB_PER_LOG2 / 16.f) - thr) * gslope);
  float g1 = fminf(0.f, (s1 * (DB_PER_LOG2 / 16.f) - thr) * gslope);

  // stage ca/cr for t=lane (g0) and t=64+lane (g1); same-wave ds order
  cab[w][2 * lane] = oneA * g0;
  cab[w][2 * lane + 1] = oneR * g0;
  cab[w][128 + 2 * lane] = oneA * g1;
  cab[w][128 + 2 * lane + 1] = oneR * g1;

  const float2* cp = (const float2*)cab[w];
  float c0 = (lane == 0) ? 0.f : BIGC;  // class 2l
  float c1 = BIGC;                      // class 2l+1
  float c128 = BIGC;                    // real only on lane 63
#pragma unroll
  for (int t = 0; t < LBLK; ++t) {
    float2 cc = cp[t];  // uniform address -> LDS broadcast
    float prev = __int_as_float(__builtin_amdgcn_update_dpp(
        __float_as_int(BIGC), __float_as_int(c1), 0x138 /*wave_shr:1*/, 0xf,
        0xf, false));  // c_old[2l-1]; lane0 -> BIGC (class -1)
    float n128 = fminf(fmaf(A, c1, cc.x), fmaf(R, c128, cc.y));  // c127=own c1
    float n1 = fminf(fmaf(A, c0, cc.x), fmaf(R, c1, cc.y));
    float n0 = fminf(fmaf(A, prev, cc.x), fmaf(R, c0, cc.y));
    c128 = n128; c1 = n1; c0 = n0;
  }
  float* outp = consts + (size_t)gblk * CSTR;
  float2 pr; pr.x = c0; pr.y = c1;
  *(float2*)(outp + 2 * lane) = pr;
  if (lane == 63) outp[128] = c128;
}

// K2: serial scan, one wave per row, 256 steps. Lanes 0-14: classes
// 8l..8l+7 (two float4); lane 15: classes 120..127 + class 128 (scalar qc;
// other lanes get BIGC -> term never wins). Per step: 9 fma + min tree +
// 4 row_shr DPP stages (all within DPP row 0) + readlane(15). PF=16
// register prefetch. Lanes 16..63 mirror lane 15, garbage isolated in
// DPP rows 1-3 (row_shr never crosses row boundaries).
__global__ __launch_bounds__(64) void k2_scan(const float* __restrict__ consts,
                                              float* __restrict__ states,
                                              const float* __restrict__ p_att,
                                              const float* __restrict__ p_rel) {
  const int r = blockIdx.x;
  const int lane = threadIdx.x;
  const float A = p_att[0], R = p_rel[0];
  const int cls0 = (lane < 15) ? 8 * lane : 120;
  float s0 = 1.f;
  for (int i = 0; i < 128; ++i) s0 *= (i < cls0) ? A : R;  // A^cls0 R^(128-cls0)
  const float rAR = A / R;
  const float sl0 = s0, sl1 = sl0 * rAR, sl2 = sl1 * rAR, sl3 = sl2 * rAR,
              sl4 = sl3 * rAR, sl5 = sl4 * rAR, sl6 = sl5 * rAR,
              sl7 = sl6 * rAR;
  const float sl8 = sl7 * rAR;  // lane15: A^128; others harmless
  const int loff = (lane < 15) ? 8 * lane : 120;
  const bool is15 = (lane == 15);

  const float* base = consts + (size_t)r * NB * CSTR;
  float* st = states + r * NB;

  float4 qa[PF], qb[PF];
  float qc[PF];
#pragma unroll
  for (int u = 0; u < PF; ++u) {
    qa[u] = *(const float4*)(base + u * CSTR + loff);
    qb[u] = *(const float4*)(base + u * CSTR + loff + 4);
    float t = base[u * CSTR + 128];
    qc[u] = is15 ? t : BIGC;
  }

  float p = 0.f;
  for (int j = 0; j < 4; ++j) {       // 4 groups of 64 steps
    float sj = 0.f;                   // lane i holds state of block j*64+i
    for (int k = 0; k < 4; ++k) {     // 4 sub-groups of PF=16
#pragma unroll
      for (int u = 0; u < PF; ++u) {
        const int b2 = j * 64 + k * PF + u;
        const int i = k * PF + u;  // step within group (uniform)
        float f0 = fmaf(sl0, p, qa[u].x);
        float f1 = fmaf(sl1, p, qa[u].y);
        float f2 = fmaf(sl2, p, qa[u].z);
        float f3 = fmaf(sl3, p, qa[u].w);
        float f4 = fmaf(sl4, p, qb[u].x);
        float f5 = fmaf(sl5, p, qb[u].y);
        float f6 = fmaf(sl6, p, qb[u].z);
        float f7 = fmaf(sl7, p, qb[u].w);
        float f8 = fmaf(sl8, p, qc[u]);
        float m = fminf(fminf(fminf(f0, f1), fminf(f2, f3)),
                        fminf(fminf(f4, f5), fminf(fminf(f6, f7), f8)));
        m = fmin_dpp_step<0x111, 0xf>(m);  // row_shr:1
        m = fmin_dpp_step<0x112, 0xf>(m);  // row_shr:2
        m = fmin_dpp_step<0x114, 0xf>(m);  // row_shr:4
        m = fmin_dpp_step<0x118, 0xf>(m);  // row_shr:8 -> lane15 = min(0..15)
        sj = (lane == i) ? p : sj;  // state at START of block b2 (old p)
        p = __int_as_float(__builtin_amdgcn_readlane(__float_as_int(m), 15));
        // refill slot u for block b2+PF (tail reads hit pad; never consumed)
        qa[u] = *(const float4*)(base + (b2 + PF) * CSTR + loff);
        qb[u] = *(const float4*)(base + (b2 + PF) * CSTR + loff + 4);
        float t2 = base[(b2 + PF) * CSTR + 128];
        qc[u] = is15 ? t2 : BIGC;
      }
    }
    st[j * 64 + lane] = sj;
  }
}

// K3: one wave per 128-frame block; lane owns frames {b*128+lane,
// b*128+64+lane} (32 samples in regs); wave replays the 128-step
// recurrence from the block-start state; applies two gains.
// Plain float4 stores (r14 ERRATA: NT stores -> partial-line RMW at HBM).
__global__ __launch_bounds__(256) void k3_apply(
    const float* __restrict__ audio, const float* __restrict__ states,
    const float* __restrict__ p_thr, const float* __restrict__ p_ratio,
    const float* __restrict__ p_makeup, const float* __restrict__ p_att,
    const float* __restrict__ p_rel, float* __restrict__ out) {
  const int tid = threadIdx.x;
  const int lane = tid & 63;
  const int w = tid >> 6;
  const int gblk = blockIdx.x * 4 + w;  // 0..16383
  const int row = gblk >> 8;
  const int b = gblk & (NB - 1);
  const float thr = p_thr[0], ratio = p_ratio[0], mk = p_makeup[0];
  const float A = p_att[0], R = p_rel[0];
  const float oneA = 1.f - A, oneR = 1.f - R;
  const float gslope = (1.f / ratio) - 1.f;

  const size_t base0 =
      (size_t)row * T_DIM + (size_t)(b * LBLK + lane) * D_FAC;
  const float4* ap0 = (const float4*)(audio + base0);
  const float4* ap1 = (const float4*)(audio + base0 + 64 * D_FAC);
  float4 x0 = ap0[0], x1 = ap0[1], x2 = ap0[2], x3 = ap0[3];
  float4 x4 = ap1[0], x5 = ap1[1], x6 = ap1[2], x7 = ap1[3];
  float s0 = sum_log2_4(x0) + sum_log2_4(x1) + sum_log2_4(x2) + sum_log2_4(x3);
  float s1 = sum_log2_4(x4) + sum_log2_4(x5) + sum_log2_4(x6) + sum_log2_4(x7);
  float g0 = fminf(0.f, (s0 * (DB_PER_LOG2 / 16.f) - thr) * gslope);
  float g1 = fminf(0.f, (s1 * (DB_PER_LOG2 / 16.f) - thr) * gslope);

  float p = states[gblk];
  float m0 = 0.f, m1 = 0.f;
  const int gi0 = __float_as_int(g0), gi1 = __float_as_int(g1);
#pragma unroll
  for (int t = 0; t < 64; ++t) {
    float gt = __int_as_float(__builtin_amdgcn_readlane(gi0, t));
    p = fminf(fmaf(A, p, oneA * gt), fmaf(R, p, oneR * gt));
    m0 = (lane == t) ? p : m0;
  }
#pragma unroll
  for (int t = 0; t < 64; ++t) {
    float gt = __int_as_float(__builtin_amdgcn_readlane(gi1, t));
    p = fminf(fmaf(A, p, oneA * gt), fmaf(R, p, oneR * gt));
    m1 = (lane == t) ? p : m1;
  }
  float mult0 = exp2f((m0 + mk) * L2TEN_OVER20);
  float mult1 = exp2f((m1 + mk) * L2TEN_OVER20);
  float4* op0 = (float4*)(out + base0);
  float4* op1 = (float4*)(out + base0 + 64 * D_FAC);
  float4 y;
  y.x = x0.x * mult0; y.y = x0.y * mult0; y.z = x0.z * mult0; y.w = x0.w * mult0; op0[0] = y;
  y.x = x1.x * mult0; y.y = x1.y * mult0; y.z = x1.z * mult0; y.w = x1.w * mult0; op0[1] = y;
  y.x = x2.x * mult0; y.y = x2.y * mult0; y.z = x2.z * mult0; y.w = x2.w * mult0; op0[2] = y;
  y.x = x3.x * mult0; y.y = x3.y * mult0; y.z = x3.z * mult0; y.w = x3.w * mult0; op0[3] = y;
  y.x = x4.x * mult1; y.y = x4.y * mult1; y.z = x4.z * mult1; y.w = x4.w * mult1; op1[0] = y;
  y.x = x5.x * mult1; y.y = x5.y * mult1; y.z = x5.z * mult1; y.w = x5.w * mult1; op1[1] = y;
  y.x = x6.x * mult1; y.y = x6.y * mult1; y.z = x6.z * mult1; y.w = x6.w * mult1; op1[2] = y;
  y.x = x7.x * mult1; y.y = x7.y * mult1; y.z = x7.z * mult1; y.w = x7.w * mult1; op1[3] = y;
}

extern "C" void kernel_launch(void* const* d_in, const int* in_sizes, int n_in,
                              void* d_out, int out_size, void* d_ws,
                              size_t ws_size, hipStream_t stream) {
  const float* audio = (const float*)d_in[0];
  const float* thr = (const float*)d_in[1];
  const float* ratio = (const float*)d_in[2];
  const float* makeup = (const float*)d_in[3];
  const float* att = (const float*)d_in[4];
  const float* rel = (const float*)d_in[5];
  float* out = (float*)d_out;

  const size_t CONSTS_BYTES =
      (size_t)(NBLK_TOT + PADBLK) * CSTR * sizeof(float);             // ~8.7 MB
  const size_t STATES_BYTES = (size_t)NBLK_TOT * sizeof(float);       // 64 KB

  float* consts;
  float* states;
  if (ws_size >= CONSTS_BYTES + STATES_BYTES) {
    consts = (float*)d_ws;
    states = (float*)((char*)d_ws + CONSTS_BYTES);
  } else {
    consts = (float*)d_out;
    states = (float*)d_ws;
  }

  hipLaunchKernelGGL(k1_compose, dim3(4096), dim3(256), 0, stream, audio, thr,
                     ratio, att, rel, consts);
  hipLaunchKernelGGL(k2_scan, dim3(64), dim3(64), 0, stream, consts, states,
                     att, rel);
  hipLaunchKernelGGL(k3_apply, dim3(4096), dim3(256), 0, stream, audio, states,
                     thr, ratio, makeup, att, rel, out);
}

// Round 19
// 126.037 us; speedup vs baseline: 5.1111x; 1.3134x over previous
//
#include <hip/hip_runtime.h>

#define B_DIM 64
#define T_DIM 524288
#define D_FAC 16
#define LBLK 128         // frames per composed block
#define NB 256           // blocks per row
#define NBLK_TOT 16384   // total blocks (B*NB)
#define NCLS 129         // LBLK+1 slope classes
#define CSTR 132         // padded stride (floats) of one block map (16B-aligned)
#define PF 16            // K2 prefetch depth (blocks)
#define PADBLK 16        // consts tail pad (blocks) for prefetch overrun
#define EPSV 1e-7f
#define BIGC 1e30f

// 20*log10(2)
#define DB_PER_LOG2 6.0205999132796239f
// log2(10)/20
#define L2TEN_OVER20 0.16609640474436813f

__device__ __forceinline__ float sum_log2_4(float4 x) {
  return __log2f(fabsf(x.x) + EPSV) + __log2f(fabsf(x.y) + EPSV) +
         __log2f(fabsf(x.z) + EPSV) + __log2f(fabsf(x.w) + EPSV);
}

template <int CTRL, int RM>
__device__ __forceinline__ float fmin_dpp_step(float v) {
  int vi = __float_as_int(v);
  int sh = __builtin_amdgcn_update_dpp(vi, vi, CTRL, RM, 0xf, false);
  return fminf(v, __int_as_float(sh));
}

// K1: one wave per 128-frame block. r18 ERRATA: full unroll of the 128-step
// DP batched LDS loads into VGPRs -> VGPR=200 -> 2 waves/SIMD -> latency
// exposed (105us at 10% occupancy). Fix: unroll 4 + launch_bounds(256,4)
// (VGPR cap 128, >=4 waves/SIMD). DP layout: lane holds classes {2l,2l+1};
// class 2l needs 2l-1 (lane l-1's second slot -> one wave_shr:1 DPP);
// 2l+1 needs own 2l; class 128 rides on lane 63.
__global__ __launch_bounds__(256, 4) void k1_compose(
    const float* __restrict__ audio, const float* __restrict__ p_thr,
    const float* __restrict__ p_ratio, const float* __restrict__ p_att,
    const float* __restrict__ p_rel, float* __restrict__ consts) {
  __shared__ float cab[4][256];  // per wave: [2t]=ca_t, [2t+1]=cr_t
  const int tid = threadIdx.x;
  const int lane = tid & 63;
  const int w = tid >> 6;
  const int gblk = blockIdx.x * 4 + w;  // 0..16383
  const int row = gblk >> 8;
  const int b = gblk & (NB - 1);
  const float thr = p_thr[0];
  const float A = p_att[0], R = p_rel[0];
  const float oneA = 1.f - A, oneR = 1.f - R;
  const float gslope = (1.f / p_ratio[0]) - 1.f;

  const size_t base0 =
      (size_t)row * T_DIM + (size_t)(b * LBLK + lane) * D_FAC;
  const float4* ap0 = (const float4*)(audio + base0);
  const float4* ap1 = (const float4*)(audio + base0 + 64 * D_FAC);
  float4 x0 = ap0[0], x1 = ap0[1], x2 = ap0[2], x3 = ap0[3];
  float4 x4 = ap1[0], x5 = ap1[1], x6 = ap1[2], x7 = ap1[3];
  float s0 = sum_log2_4(x0) + sum_log2_4(x1) + sum_log2_4(x2) + sum_log2_4(x3);
  float s1 = sum_log2_4(x4) + sum_log2_4(x5) + sum_log2_4(x6) + sum_log2_4(x7);
  float g0 = fminf(0.f, (s0 * (DB_PER_LOG2 / 16.f) - thr) * gslope);
  float g1 = fminf(0.f, (s1 * (DB_PER_LOG2 / 16.f) - thr) * gslope);

  // stage ca/cr for t=lane (g0) and t=64+lane (g1); same-wave ds order
  cab[w][2 * lane] = oneA * g0;
  cab[w][2 * lane + 1] = oneR * g0;
  cab[w][128 + 2 * lane] = oneA * g1;
  cab[w][128 + 2 * lane + 1] = oneR * g1;

  const float2* cp = (const float2*)cab[w];
  float c0 = (lane == 0) ? 0.f : BIGC;  // class 2l
  float c1 = BIGC;                      // class 2l+1
  float c128 = BIGC;                    // real only on lane 63
#pragma unroll 4
  for (int t = 0; t < LBLK; ++t) {
    float2 cc = cp[t];  // uniform address -> LDS broadcast
    float prev = __int_as_float(__builtin_amdgcn_update_dpp(
        __float_as_int(BIGC), __float_as_int(c1), 0x138 /*wave_shr:1*/, 0xf,
        0xf, false));  // c_old[2l-1]; lane0 -> BIGC (class -1)
    float n128 = fminf(fmaf(A, c1, cc.x), fmaf(R, c128, cc.y));  // c127=own c1
    float n1 = fminf(fmaf(A, c0, cc.x), fmaf(R, c1, cc.y));
    float n0 = fminf(fmaf(A, prev, cc.x), fmaf(R, c0, cc.y));
    c128 = n128; c1 = n1; c0 = n0;
  }
  float* outp = consts + (size_t)gblk * CSTR;
  float2 pr; pr.x = c0; pr.y = c1;
  *(float2*)(outp + 2 * lane) = pr;
  if (lane == 63) outp[128] = c128;
}

// K2: serial scan, one wave per row, 256 steps. Lanes 0-14: classes
// 8l..8l+7 (two float4); lane 15: classes 120..127 + class 128 (scalar qc;
// other lanes get BIGC -> term never wins). Per step: 9 fma + min tree +
// 4 row_shr DPP stages (all within DPP row 0) + readlane(15). PF=16
// register prefetch. Lanes 16..63 mirror lane 15, garbage isolated in
// DPP rows 1-3 (row_shr never crosses row boundaries).
__global__ __launch_bounds__(64) void k2_scan(const float* __restrict__ consts,
                                              float* __restrict__ states,
                                              const float* __restrict__ p_att,
                                              const float* __restrict__ p_rel) {
  const int r = blockIdx.x;
  const int lane = threadIdx.x;
  const float A = p_att[0], R = p_rel[0];
  const int cls0 = (lane < 15) ? 8 * lane : 120;
  float s0 = 1.f;
  for (int i = 0; i < 128; ++i) s0 *= (i < cls0) ? A : R;  // A^cls0 R^(128-cls0)
  const float rAR = A / R;
  const float sl0 = s0, sl1 = sl0 * rAR, sl2 = sl1 * rAR, sl3 = sl2 * rAR,
              sl4 = sl3 * rAR, sl5 = sl4 * rAR, sl6 = sl5 * rAR,
              sl7 = sl6 * rAR;
  const float sl8 = sl7 * rAR;  // lane15: A^128; others harmless
  const int loff = (lane < 15) ? 8 * lane : 120;
  const bool is15 = (lane == 15);

  const float* base = consts + (size_t)r * NB * CSTR;
  float* st = states + r * NB;

  float4 qa[PF], qb[PF];
  float qc[PF];
#pragma unroll
  for (int u = 0; u < PF; ++u) {
    qa[u] = *(const float4*)(base + u * CSTR + loff);
    qb[u] = *(const float4*)(base + u * CSTR + loff + 4);
    float t = base[u * CSTR + 128];
    qc[u] = is15 ? t : BIGC;
  }

  float p = 0.f;
  for (int j = 0; j < 4; ++j) {       // 4 groups of 64 steps
    float sj = 0.f;                   // lane i holds state of block j*64+i
    for (int k = 0; k < 4; ++k) {     // 4 sub-groups of PF=16
#pragma unroll
      for (int u = 0; u < PF; ++u) {
        const int b2 = j * 64 + k * PF + u;
        const int i = k * PF + u;  // step within group (uniform)
        float f0 = fmaf(sl0, p, qa[u].x);
        float f1 = fmaf(sl1, p, qa[u].y);
        float f2 = fmaf(sl2, p, qa[u].z);
        float f3 = fmaf(sl3, p, qa[u].w);
        float f4 = fmaf(sl4, p, qb[u].x);
        float f5 = fmaf(sl5, p, qb[u].y);
        float f6 = fmaf(sl6, p, qb[u].z);
        float f7 = fmaf(sl7, p, qb[u].w);
        float f8 = fmaf(sl8, p, qc[u]);
        float m = fminf(fminf(fminf(f0, f1), fminf(f2, f3)),
                        fminf(fminf(f4, f5), fminf(fminf(f6, f7), f8)));
        m = fmin_dpp_step<0x111, 0xf>(m);  // row_shr:1
        m = fmin_dpp_step<0x112, 0xf>(m);  // row_shr:2
        m = fmin_dpp_step<0x114, 0xf>(m);  // row_shr:4
        m = fmin_dpp_step<0x118, 0xf>(m);  // row_shr:8 -> lane15 = min(0..15)
        sj = (lane == i) ? p : sj;  // state at START of block b2 (old p)
        p = __int_as_float(__builtin_amdgcn_readlane(__float_as_int(m), 15));
        // refill slot u for block b2+PF (tail reads hit pad; never consumed)
        qa[u] = *(const float4*)(base + (b2 + PF) * CSTR + loff);
        qb[u] = *(const float4*)(base + (b2 + PF) * CSTR + loff + 4);
        float t2 = base[(b2 + PF) * CSTR + 128];
        qc[u] = is15 ? t2 : BIGC;
      }
    }
    st[j * 64 + lane] = sj;
  }
}

// K3: one wave per 128-frame block; lane owns frames {b*128+lane,
// b*128+64+lane} (32 samples in regs); wave replays the 128-step
// recurrence from the block-start state; applies two gains.
// Plain float4 stores (r14 ERRATA: NT stores -> partial-line RMW at HBM).
__global__ __launch_bounds__(256) void k3_apply(
    const float* __restrict__ audio, const float* __restrict__ states,
    const float* __restrict__ p_thr, const float* __restrict__ p_ratio,
    const float* __restrict__ p_makeup, const float* __restrict__ p_att,
    const float* __restrict__ p_rel, float* __restrict__ out) {
  const int tid = threadIdx.x;
  const int lane = tid & 63;
  const int w = tid >> 6;
  const int gblk = blockIdx.x * 4 + w;  // 0..16383
  const int row = gblk >> 8;
  const int b = gblk & (NB - 1);
  const float thr = p_thr[0], ratio = p_ratio[0], mk = p_makeup[0];
  const float A = p_att[0], R = p_rel[0];
  const float oneA = 1.f - A, oneR = 1.f - R;
  const float gslope = (1.f / ratio) - 1.f;

  const size_t base0 =
      (size_t)row * T_DIM + (size_t)(b * LBLK + lane) * D_FAC;
  const float4* ap0 = (const float4*)(audio + base0);
  const float4* ap1 = (const float4*)(audio + base0 + 64 * D_FAC);
  float4 x0 = ap0[0], x1 = ap0[1], x2 = ap0[2], x3 = ap0[3];
  float4 x4 = ap1[0], x5 = ap1[1], x6 = ap1[2], x7 = ap1[3];
  float s0 = sum_log2_4(x0) + sum_log2_4(x1) + sum_log2_4(x2) + sum_log2_4(x3);
  float s1 = sum_log2_4(x4) + sum_log2_4(x5) + sum_log2_4(x6) + sum_log2_4(x7);
  float g0 = fminf(0.f, (s0 * (DB_PER_LOG2 / 16.f) - thr) * gslope);
  float g1 = fminf(0.f, (s1 * (DB_PER_LOG2 / 16.f) - thr) * gslope);

  float p = states[gblk];
  float m0 = 0.f, m1 = 0.f;
  const int gi0 = __float_as_int(g0), gi1 = __float_as_int(g1);
#pragma unroll
  for (int t = 0; t < 64; ++t) {
    float gt = __int_as_float(__builtin_amdgcn_readlane(gi0, t));
    p = fminf(fmaf(A, p, oneA * gt), fmaf(R, p, oneR * gt));
    m0 = (lane == t) ? p : m0;
  }
#pragma unroll
  for (int t = 0; t < 64; ++t) {
    float gt = __int_as_float(__builtin_amdgcn_readlane(gi1, t));
    p = fminf(fmaf(A, p, oneA * gt), fmaf(R, p, oneR * gt));
    m1 = (lane == t) ? p : m1;
  }
  float mult0 = exp2f((m0 + mk) * L2TEN_OVER20);
  float mult1 = exp2f((m1 + mk) * L2TEN_OVER20);
  float4* op0 = (float4*)(out + base0);
  float4* op1 = (float4*)(out + base0 + 64 * D_FAC);
  float4 y;
  y.x = x0.x * mult0; y.y = x0.y * mult0; y.z = x0.z * mult0; y.w = x0.w * mult0; op0[0] = y;
  y.x = x1.x * mult0; y.y = x1.y * mult0; y.z = x1.z * mult0; y.w = x1.w * mult0; op0[1] = y;
  y.x = x2.x * mult0; y.y = x2.y * mult0; y.z = x2.z * mult0; y.w = x2.w * mult0; op0[2] = y;
  y.x = x3.x * mult0; y.y = x3.y * mult0; y.z = x3.z * mult0; y.w = x3.w * mult0; op0[3] = y;
  y.x = x4.x * mult1; y.y = x4.y * mult1; y.z = x4.z * mult1; y.w = x4.w * mult1; op1[0] = y;
  y.x = x5.x * mult1; y.y = x5.y * mult1; y.z = x5.z * mult1; y.w = x5.w * mult1; op1[1] = y;
  y.x = x6.x * mult1; y.y = x6.y * mult1; y.z = x6.z * mult1; y.w = x6.w * mult1; op1[2] = y;
  y.x = x7.x * mult1; y.y = x7.y * mult1; y.z = x7.z * mult1; y.w = x7.w * mult1; op1[3] = y;
}

extern "C" void kernel_launch(void* const* d_in, const int* in_sizes, int n_in,
                              void* d_out, int out_size, void* d_ws,
                              size_t ws_size, hipStream_t stream) {
  const float* audio = (const float*)d_in[0];
  const float* thr = (const float*)d_in[1];
  const float* ratio = (const float*)d_in[2];
  const float* makeup = (const float*)d_in[3];
  const float* att = (const float*)d_in[4];
  const float* rel = (const float*)d_in[5];
  float* out = (float*)d_out;

  const size_t CONSTS_BYTES =
      (size_t)(NBLK_TOT + PADBLK) * CSTR * sizeof(float);             // ~8.7 MB
  const size_t STATES_BYTES = (size_t)NBLK_TOT * sizeof(float);       // 64 KB

  float* consts;
  float* states;
  if (ws_size >= CONSTS_BYTES + STATES_BYTES) {
    consts = (float*)d_ws;
    states = (float*)((char*)d_ws + CONSTS_BYTES);
  } else {
    consts = (float*)d_out;
    states = (float*)d_ws;
  }

  hipLaunchKernelGGL(k1_compose, dim3(4096), dim3(256), 0, stream, audio, thr,
                     ratio, att, rel, consts);
  hipLaunchKernelGGL(k2_scan, dim3(64), dim3(64), 0, stream, consts, states,
                     att, rel);
  hipLaunchKernelGGL(k3_apply, dim3(4096), dim3(256), 0, stream, audio, states,
                     thr, ratio, makeup, att, rel, out);
}

// Round 20
// 118.489 us; speedup vs baseline: 5.4367x; 1.0637x over previous
//
#include <hip/hip_runtime.h>

#define B_DIM 64
#define T_DIM 524288
#define D_FAC 16
#define LBLK 128         // frames per composed block
#define NB 256           // blocks per row
#define NBLK_TOT 16384   // total blocks (B*NB)
#define NCLS 129         // LBLK+1 slope classes
#define CSTR 132         // padded stride (floats) of one block map (16B-aligned)
#define PF 16            // K2 prefetch depth (blocks)
#define PADBLK 16        // consts tail pad (blocks) for prefetch overrun
#define EPSV 1e-7f
#define BIGC 1e30f

// 20*log10(2)
#define DB_PER_LOG2 6.0205999132796239f
// log2(10)/20
#define L2TEN_OVER20 0.16609640474436813f

__device__ __forceinline__ float sum_log2_4(float4 x) {
  return __log2f(fabsf(x.x) + EPSV) + __log2f(fabsf(x.y) + EPSV) +
         __log2f(fabsf(x.z) + EPSV) + __log2f(fabsf(x.w) + EPSV);
}

template <int CTRL, int RM>
__device__ __forceinline__ float fmin_dpp_step(float v) {
  int vi = __float_as_int(v);
  int sh = __builtin_amdgcn_update_dpp(vi, vi, CTRL, RM, 0xf, false);
  return fminf(v, __int_as_float(sh));
}

// full-wave sum reduce; result valid on lane 63. Zero-fill (bound_ctrl=1)
// row_shr steps, then masked row_bcast15/31 folds (out-of-mask lanes add 0).
__device__ __forceinline__ float wave_sum63(float v) {
#define ADD_DPP(CTRL, RM)                                                 \
  v += __int_as_float(__builtin_amdgcn_update_dpp(                        \
      0, __float_as_int(v), CTRL, RM, 0xf, true));
  ADD_DPP(0x111, 0xf)  // row_shr:1
  ADD_DPP(0x112, 0xf)  // row_shr:2
  ADD_DPP(0x114, 0xf)  // row_shr:4
  ADD_DPP(0x118, 0xf)  // row_shr:8  -> lane15 of each row = row sum
  ADD_DPP(0x142, 0xa)  // row_bcast:15 -> lane31 = rows0-1, lane63 = rows2-3
  ADD_DPP(0x143, 0xc)  // row_bcast:31 -> lane63 = all
#undef ADD_DPP
  return v;
}

// K1: one wave per 128-frame block. DP loop cut 11 -> 8 inst/step: class
// 128 (all-attack path) never branches, so its constant is the LINEAR form
// c128 = (1-A) * sum_t A^(127-t) g_t -- computed after the loop via
// weighted contributions + one DPP add-reduce (replaces 384 in-loop inst;
// the in-loop R-branch could never win since c128 is BIGC until t=127).
// Layout: lane holds classes {2l, 2l+1}; class 2l needs 2l-1 (lane l-1's
// second slot -> one wave_shr:1 DPP); 2l+1 needs own 2l.
// r18 ERRATA: full unroll -> VGPR 200 -> 10% occupancy; keep unroll 4 +
// launch_bounds(256,4).
__global__ __launch_bounds__(256, 4) void k1_compose(
    const float* __restrict__ audio, const float* __restrict__ p_thr,
    const float* __restrict__ p_ratio, const float* __restrict__ p_att,
    const float* __restrict__ p_rel, float* __restrict__ consts) {
  __shared__ float cab[4][256];  // per wave: [2t]=ca_t, [2t+1]=cr_t
  const int tid = threadIdx.x;
  const int lane = tid & 63;
  const int w = tid >> 6;
  const int gblk = blockIdx.x * 4 + w;  // 0..16383
  const int row = gblk >> 8;
  const int b = gblk & (NB - 1);
  const float thr = p_thr[0];
  const float A = p_att[0], R = p_rel[0];
  const float oneA = 1.f - A, oneR = 1.f - R;
  const float gslope = (1.f / p_ratio[0]) - 1.f;

  const size_t base0 =
      (size_t)row * T_DIM + (size_t)(b * LBLK + lane) * D_FAC;
  const float4* ap0 = (const float4*)(audio + base0);
  const float4* ap1 = (const float4*)(audio + base0 + 64 * D_FAC);
  float4 x0 = ap0[0], x1 = ap0[1], x2 = ap0[2], x3 = ap0[3];
  float4 x4 = ap1[0], x5 = ap1[1], x6 = ap1[2], x7 = ap1[3];
  float s0 = sum_log2_4(x0) + sum_log2_4(x1) + sum_log2_4(x2) + sum_log2_4(x3);
  float s1 = sum_log2_4(x4) + sum_log2_4(x5) + sum_log2_4(x6) + sum_log2_4(x7);
  float g0 = fminf(0.f, (s0 * (DB_PER_LOG2 / 16.f) - thr) * gslope);
  float g1 = fminf(0.f, (s1 * (DB_PER_LOG2 / 16.f) - thr) * gslope);

  // stage ca/cr for t=lane (g0) and t=64+lane (g1); same-wave ds order
  cab[w][2 * lane] = oneA * g0;
  cab[w][2 * lane + 1] = oneR * g0;
  cab[w][128 + 2 * lane] = oneA * g1;
  cab[w][128 + 2 * lane + 1] = oneR * g1;

  const float2* cp = (const float2*)cab[w];
  float c0 = (lane == 0) ? 0.f : BIGC;  // class 2l
  float c1 = BIGC;                      // class 2l+1
#pragma unroll 4
  for (int t = 0; t < LBLK; ++t) {
    float2 cc = cp[t];  // uniform address -> LDS broadcast
    float prev = __int_as_float(__builtin_amdgcn_update_dpp(
        __float_as_int(BIGC), __float_as_int(c1), 0x138 /*wave_shr:1*/, 0xf,
        0xf, false));  // c_old[2l-1]; lane0 -> BIGC (class -1)
    float n1 = fminf(fmaf(A, c0, cc.x), fmaf(R, c1, cc.y));
    float n0 = fminf(fmaf(A, prev, cc.x), fmaf(R, c0, cc.y));
    c1 = n1; c0 = n0;
  }

  // class 128 = all-attack linear form
  const float l2A = __log2f(A);
  float h = oneA * exp2f((float)(127 - lane) * l2A) * g0 +
            oneA * exp2f((float)(63 - lane) * l2A) * g1;
  float c128 = wave_sum63(h);  // valid on lane 63

  float* outp = consts + (size_t)gblk * CSTR;
  float2 pr; pr.x = c0; pr.y = c1;
  *(float2*)(outp + 2 * lane) = pr;
  if (lane == 63) outp[128] = c128;
}

// K2: serial scan, one wave per row, 256 steps. Lanes 0-14: classes
// 8l..8l+7 (two float4); lane 15: classes 120..127 + class 128 (scalar qc;
// other lanes get BIGC -> term never wins). Per step: 9 fma + min tree +
// 4 row_shr DPP stages (all within DPP row 0) + readlane(15). PF=16
// register prefetch. Lanes 16..63 mirror lane 15, garbage isolated in
// DPP rows 1-3 (row_shr never crosses row boundaries).
__global__ __launch_bounds__(64) void k2_scan(const float* __restrict__ consts,
                                              float* __restrict__ states,
                                              const float* __restrict__ p_att,
                                              const float* __restrict__ p_rel) {
  const int r = blockIdx.x;
  const int lane = threadIdx.x;
  const float A = p_att[0], R = p_rel[0];
  const int cls0 = (lane < 15) ? 8 * lane : 120;
  float s0 = 1.f;
  for (int i = 0; i < 128; ++i) s0 *= (i < cls0) ? A : R;  // A^cls0 R^(128-cls0)
  const float rAR = A / R;
  const float sl0 = s0, sl1 = sl0 * rAR, sl2 = sl1 * rAR, sl3 = sl2 * rAR,
              sl4 = sl3 * rAR, sl5 = sl4 * rAR, sl6 = sl5 * rAR,
              sl7 = sl6 * rAR;
  const float sl8 = sl7 * rAR;  // lane15: A^128; others harmless
  const int loff = (lane < 15) ? 8 * lane : 120;
  const bool is15 = (lane == 15);

  const float* base = consts + (size_t)r * NB * CSTR;
  float* st = states + r * NB;

  float4 qa[PF], qb[PF];
  float qc[PF];
#pragma unroll
  for (int u = 0; u < PF; ++u) {
    qa[u] = *(const float4*)(base + u * CSTR + loff);
    qb[u] = *(const float4*)(base + u * CSTR + loff + 4);
    float t = base[u * CSTR + 128];
    qc[u] = is15 ? t : BIGC;
  }

  float p = 0.f;
  for (int j = 0; j < 4; ++j) {       // 4 groups of 64 steps
    float sj = 0.f;                   // lane i holds state of block j*64+i
    for (int k = 0; k < 4; ++k) {     // 4 sub-groups of PF=16
#pragma unroll
      for (int u = 0; u < PF; ++u) {
        const int b2 = j * 64 + k * PF + u;
        const int i = k * PF + u;  // step within group (uniform)
        float f0 = fmaf(sl0, p, qa[u].x);
        float f1 = fmaf(sl1, p, qa[u].y);
        float f2 = fmaf(sl2, p, qa[u].z);
        float f3 = fmaf(sl3, p, qa[u].w);
        float f4 = fmaf(sl4, p, qb[u].x);
        float f5 = fmaf(sl5, p, qb[u].y);
        float f6 = fmaf(sl6, p, qb[u].z);
        float f7 = fmaf(sl7, p, qb[u].w);
        float f8 = fmaf(sl8, p, qc[u]);
        float m = fminf(fminf(fminf(f0, f1), fminf(f2, f3)),
                        fminf(fminf(f4, f5), fminf(fminf(f6, f7), f8)));
        m = fmin_dpp_step<0x111, 0xf>(m);  // row_shr:1
        m = fmin_dpp_step<0x112, 0xf>(m);  // row_shr:2
        m = fmin_dpp_step<0x114, 0xf>(m);  // row_shr:4
        m = fmin_dpp_step<0x118, 0xf>(m);  // row_shr:8 -> lane15 = min(0..15)
        sj = (lane == i) ? p : sj;  // state at START of block b2 (old p)
        p = __int_as_float(__builtin_amdgcn_readlane(__float_as_int(m), 15));
        // refill slot u for block b2+PF (tail reads hit pad; never consumed)
        qa[u] = *(const float4*)(base + (b2 + PF) * CSTR + loff);
        qb[u] = *(const float4*)(base + (b2 + PF) * CSTR + loff + 4);
        float t2 = base[(b2 + PF) * CSTR + 128];
        qc[u] = is15 ? t2 : BIGC;
      }
    }
    st[j * 64 + lane] = sj;
  }
}

// K3: one wave per 128-frame block; lane owns frames {b*128+lane,
// b*128+64+lane} (32 samples in regs); wave replays the 128-step
// recurrence from the block-start state; applies two gains.
// Plain float4 stores (r14 ERRATA: NT stores -> partial-line RMW at HBM).
__global__ __launch_bounds__(256) void k3_apply(
    const float* __restrict__ audio, const float* __restrict__ states,
    const float* __restrict__ p_thr, const float* __restrict__ p_ratio,
    const float* __restrict__ p_makeup, const float* __restrict__ p_att,
    const float* __restrict__ p_rel, float* __restrict__ out) {
  const int tid = threadIdx.x;
  const int lane = tid & 63;
  const int w = tid >> 6;
  const int gblk = blockIdx.x * 4 + w;  // 0..16383
  const int row = gblk >> 8;
  const int b = gblk & (NB - 1);
  const float thr = p_thr[0], ratio = p_ratio[0], mk = p_makeup[0];
  const float A = p_att[0], R = p_rel[0];
  const float oneA = 1.f - A, oneR = 1.f - R;
  const float gslope = (1.f / ratio) - 1.f;

  const size_t base0 =
      (size_t)row * T_DIM + (size_t)(b * LBLK + lane) * D_FAC;
  const float4* ap0 = (const float4*)(audio + base0);
  const float4* ap1 = (const float4*)(audio + base0 + 64 * D_FAC);
  float4 x0 = ap0[0], x1 = ap0[1], x2 = ap0[2], x3 = ap0[3];
  float4 x4 = ap1[0], x5 = ap1[1], x6 = ap1[2], x7 = ap1[3];
  float s0 = sum_log2_4(x0) + sum_log2_4(x1) + sum_log2_4(x2) + sum_log2_4(x3);
  float s1 = sum_log2_4(x4) + sum_log2_4(x5) + sum_log2_4(x6) + sum_log2_4(x7);
  float g0 = fminf(0.f, (s0 * (DB_PER_LOG2 / 16.f) - thr) * gslope);
  float g1 = fminf(0.f, (s1 * (DB_PER_LOG2 / 16.f) - thr) * gslope);

  float p = states[gblk];
  float m0 = 0.f, m1 = 0.f;
  const int gi0 = __float_as_int(g0), gi1 = __float_as_int(g1);
#pragma unroll
  for (int t = 0; t < 64; ++t) {
    float gt = __int_as_float(__builtin_amdgcn_readlane(gi0, t));
    p = fminf(fmaf(A, p, oneA * gt), fmaf(R, p, oneR * gt));
    m0 = (lane == t) ? p : m0;
  }
#pragma unroll
  for (int t = 0; t < 64; ++t) {
    float gt = __int_as_float(__builtin_amdgcn_readlane(gi1, t));
    p = fminf(fmaf(A, p, oneA * gt), fmaf(R, p, oneR * gt));
    m1 = (lane == t) ? p : m1;
  }
  float mult0 = exp2f((m0 + mk) * L2TEN_OVER20);
  float mult1 = exp2f((m1 + mk) * L2TEN_OVER20);
  float4* op0 = (float4*)(out + base0);
  float4* op1 = (float4*)(out + base0 + 64 * D_FAC);
  float4 y;
  y.x = x0.x * mult0; y.y = x0.y * mult0; y.z = x0.z * mult0; y.w = x0.w * mult0; op0[0] = y;
  y.x = x1.x * mult0; y.y = x1.y * mult0; y.z = x1.z * mult0; y.w = x1.w * mult0; op0[1] = y;
  y.x = x2.x * mult0; y.y = x2.y * mult0; y.z = x2.z * mult0; y.w = x2.w * mult0; op0[2] = y;
  y.x = x3.x * mult0; y.y = x3.y * mult0; y.z = x3.z * mult0; y.w = x3.w * mult0; op0[3] = y;
  y.x = x4.x * mult1; y.y = x4.y * mult1; y.z = x4.z * mult1; y.w = x4.w * mult1; op1[0] = y;
  y.x = x5.x * mult1; y.y = x5.y * mult1; y.z = x5.z * mult1; y.w = x5.w * mult1; op1[1] = y;
  y.x = x6.x * mult1; y.y = x6.y * mult1; y.z = x6.z * mult1; y.w = x6.w * mult1; op1[2] = y;
  y.x = x7.x * mult1; y.y = x7.y * mult1; y.z = x7.z * mult1; y.w = x7.w * mult1; op1[3] = y;
}

extern "C" void kernel_launch(void* const* d_in, const int* in_sizes, int n_in,
                              void* d_out, int out_size, void* d_ws,
                              size_t ws_size, hipStream_t stream) {
  const float* audio = (const float*)d_in[0];
  const float* thr = (const float*)d_in[1];
  const float* ratio = (const float*)d_in[2];
  const float* makeup = (const float*)d_in[3];
  const float* att = (const float*)d_in[4];
  const float* rel = (const float*)d_in[5];
  float* out = (float*)d_out;

  const size_t CONSTS_BYTES =
      (size_t)(NBLK_TOT + PADBLK) * CSTR * sizeof(float);             // ~8.7 MB
  const size_t STATES_BYTES = (size_t)NBLK_TOT * sizeof(float);       // 64 KB

  float* consts;
  float* states;
  if (ws_size >= CONSTS_BYTES + STATES_BYTES) {
    consts = (float*)d_ws;
    states = (float*)((char*)d_ws + CONSTS_BYTES);
  } else {
    consts = (float*)d_out;
    states = (float*)d_ws;
  }

  hipLaunchKernelGGL(k1_compose, dim3(4096), dim3(256), 0, stream, audio, thr,
                     ratio, att, rel, consts);
  hipLaunchKernelGGL(k2_scan, dim3(64), dim3(64), 0, stream, consts, states,
                     att, rel);
  hipLaunchKernelGGL(k3_apply, dim3(4096), dim3(256), 0, stream, audio, states,
                     thr, ratio, makeup, att, rel, out);
}